// Round 16
// baseline (107.367 us; speedup 1.0000x reference)
//
#include <hip/hip_runtime.h>
#include <stdint.h>

#define NN 6144
#define NUSER 4096
#define RR 2
#define KK 3
#define FIN 25
#define FOUT 64
#define DD2 64
#define CAP 192

#define NWAVE 2048                     // persistent waves
#define ROWS_PER_WAVE 4                // 8192 rows total

typedef int int4v __attribute__((ext_vector_type(4)));

__device__ __forceinline__ float wave_reduce_sum(float v) {
    #pragma unroll
    for (int off = 32; off >= 1; off >>= 1) v += __shfl_xor(v, off);
    return v;
}
__device__ __forceinline__ unsigned short f2bf(float x) {   // RNE
    unsigned int u = __float_as_uint(x);
    unsigned int r = (u + 0x7fffu + ((u >> 16) & 1u)) >> 16;
    return (unsigned short)r;
}
__device__ __forceinline__ float bf2f(unsigned short b) {
    return __uint_as_float(((unsigned int)b) << 16);
}

// ---- k1: one wave per (r,n), ALL n: hp 3 heads (packed bf16) + s,d.
__global__ __launch_bounds__(256) void k1_proj(
    const float* __restrict__ h, const float* __restrict__ w,
    const float* __restrict__ asrc, const float* __restrict__ adst,
    ushort4* __restrict__ hpq, float4* __restrict__ sq, float4* __restrict__ dq)
{
    const int wid  = threadIdx.x >> 6;
    const int lane = threadIdx.x & 63;
    const int row  = blockIdx.x * 4 + wid;     // r*NN + n
    const int r    = row / NN;
    const int n    = row % NN;

    const float* hrow = h + (size_t)n * FIN;
    float acc[KK];
    #pragma unroll
    for (int k = 0; k < KK; ++k) {
        const float* wp = w + ((size_t)(r * KK + k) * FIN) * FOUT + lane;
        float a = 0.f;
        #pragma unroll
        for (int f = 0; f < FIN; ++f) a += hrow[f] * wp[f * FOUT];
        acc[k] = a;
    }

    ushort4 pk;
    pk.x = f2bf(acc[0]); pk.y = f2bf(acc[1]); pk.z = f2bf(acc[2]); pk.w = 0;
    hpq[(size_t)row * FOUT + lane] = pk;

    float sv0 = wave_reduce_sum(acc[0] * asrc[(r * KK + 0) * FOUT + lane]);
    float sv1 = wave_reduce_sum(acc[1] * asrc[(r * KK + 1) * FOUT + lane]);
    float sv2 = wave_reduce_sum(acc[2] * asrc[(r * KK + 2) * FOUT + lane]);
    float dv0 = wave_reduce_sum(acc[0] * adst[(r * KK + 0) * FOUT + lane]);
    float dv1 = wave_reduce_sum(acc[1] * adst[(r * KK + 1) * FOUT + lane]);
    float dv2 = wave_reduce_sum(acc[2] * adst[(r * KK + 2) * FOUT + lane]);
    if (lane == 0) {
        sq[row] = make_float4(sv0, sv1, sv2, 0.f);
        dq[row] = make_float4(dv0, dv1, dv2, 0.f);
    }
}

// ---- kSG: persistent-wave fused scan+GAT+fusion+classifier.
// Wave g (of 2048) owns urows {g, g+2048, g+4096, g+6144}: both relations
// for nodes g and g+2048. Per row: full ballot scan -> LDS list, then
// logits+PV gather. Sequential per wave; waves decorrelate across rows so
// scans overlap gathers CU-wide; instantaneous HBM footprint is a 48MB
// stripe instead of 192MB. Epilogue: in-wave semantic fusion + classifier.
__global__ __launch_bounds__(256) void kSG(
    const int* __restrict__ hadj, const ushort4* __restrict__ hpq,
    const float4* __restrict__ sq, const float4* __restrict__ dq,
    const float* __restrict__ bias, const float* __restrict__ h,
    const float* __restrict__ aw1, const float* __restrict__ aw2,
    const float* __restrict__ am, const float* __restrict__ fcw,
    const float* __restrict__ fcb, float* __restrict__ out)
{
    const int wid  = threadIdx.x >> 6;
    const int lane = threadIdx.x & 63;
    const int g    = blockIdx.x * 4 + wid;     // persistent wave id, 0..2047

    __shared__ int   nbr_s[4][CAP];
    __shared__ float pw_s[4][3][CAP];
    __shared__ float emb_sh[4][ROWS_PER_WAVE][FOUT];
    int* nbr = nbr_s[wid];
    float (*pw)[CAP] = pw_s[wid];

    const unsigned long long below = (1ull << lane) - 1ull;

    #pragma unroll 1
    for (int rr = 0; rr < ROWS_PER_WAVE; ++rr) {
        const int urow = g + rr * NWAVE;       // r*NUSER + n
        const int r    = urow >> 12;           // /4096
        const int n    = urow & 4095;

        // ---- phase 1: scan row -> LDS neighbor list (8-deep load pipeline)
        const int* rowp = hadj + ((size_t)r * NN + n) * NN;
        int base = 0;
        #pragma unroll 8
        for (int t = 0; t < 24; ++t) {
            const int m0 = t * 256 + lane * 4;
            const int4v v = *reinterpret_cast<const int4v*>(rowp + m0);
            const unsigned long long b0 = __ballot(v.x != 0);
            const unsigned long long b1 = __ballot(v.y != 0);
            const unsigned long long b2 = __ballot(v.z != 0);
            const unsigned long long b3 = __ballot(v.w != 0);
            const int n0 = __popcll(b0), n1 = __popcll(b1);
            const int n2 = __popcll(b2), n3 = __popcll(b3);
            const int o0 = base + __popcll(b0 & below);
            const int o1 = base + n0 + __popcll(b1 & below);
            const int o2 = base + n0 + n1 + __popcll(b2 & below);
            const int o3 = base + n0 + n1 + n2 + __popcll(b3 & below);
            if (v.x && o0 < CAP) nbr[o0] = m0 + 0;
            if (v.y && o1 < CAP) nbr[o1] = m0 + 1;
            if (v.z && o2 < CAP) nbr[o2] = m0 + 2;
            if (v.w && o3 < CAP) nbr[o3] = m0 + 3;
            base += n0 + n1 + n2 + n3;
        }
        const int count = base > CAP ? CAP : base;

        // ---- phase 2: logits (single-pass softmax, no max-shift)
        const float4 sv = sq[(size_t)r * NN + n];
        const float4* dqr = dq + (size_t)r * NN;
        float ss0 = 0.f, ss1 = 0.f, ss2 = 0.f;
        for (int j = lane; j < count; j += 64) {
            const float4 dv = dqr[nbr[j]];
            float e0 = sv.x + dv.x; e0 = (e0 >= 0.f) ? e0 : 0.2f * e0;
            float e1 = sv.y + dv.y; e1 = (e1 >= 0.f) ? e1 : 0.2f * e1;
            float e2 = sv.z + dv.z; e2 = (e2 >= 0.f) ? e2 : 0.2f * e2;
            float p0 = __expf(e0); pw[0][j] = p0; ss0 += p0;
            float p1 = __expf(e1); pw[1][j] = p1; ss1 += p1;
            float p2 = __expf(e2); pw[2][j] = p2; ss2 += p2;
        }
        ss0 = wave_reduce_sum(ss0);
        ss1 = wave_reduce_sum(ss1);
        ss2 = wave_reduce_sum(ss2);

        // ---- phase 3: PV gather (8-deep)
        const ushort4* hq = hpq + ((size_t)r * NN) * FOUT + lane;
        float a0 = 0.f, a1 = 0.f, a2 = 0.f;
        int j = 0;
        for (; j + 8 <= count; j += 8) {
            #pragma unroll
            for (int u = 0; u < 8; ++u) {
                const ushort4 v = hq[(size_t)nbr[j + u] * FOUT];
                a0 += pw[0][j + u] * bf2f(v.x);
                a1 += pw[1][j + u] * bf2f(v.y);
                a2 += pw[2][j + u] * bf2f(v.z);
            }
        }
        for (; j < count; ++j) {
            const ushort4 v = hq[(size_t)nbr[j] * FOUT];
            a0 += pw[0][j] * bf2f(v.x);
            a1 += pw[1][j] * bf2f(v.y);
            a2 += pw[2][j] * bf2f(v.z);
        }

        emb_sh[wid][rr][lane] = (a0 / ss0 + a1 / ss1 + a2 / ss2) * (1.f / 3.f)
                              + bias[r * FOUT + lane];
    }

    // ---- epilogue: fusion + classifier for nodes g and g+2048 (in-wave;
    // emb_sh written and read by the same wave -> no barrier needed).
    const int o = lane;
    #pragma unroll
    for (int a = 0; a < 2; ++a) {
        const int n = g + a * NWAVE;
        const float ta0 = emb_sh[wid][a][o];       // rr=a   -> r0
        const float ta1 = emb_sh[wid][a + 2][o];   // rr=a+2 -> r1

        float fa = 0.f;
        const float* hrow = h + (size_t)n * FIN;
        #pragma unroll
        for (int f = 0; f < FIN; ++f) fa += hrow[f] * aw1[f * DD2 + o];

        float e[2];
        #pragma unroll
        for (int q = 0; q < 2; ++q) {
            float t = fa;
            const float* es = emb_sh[wid][a + 2 * q];
            #pragma unroll 8
            for (int jj = 0; jj < FOUT; ++jj) t += es[jj] * aw2[jj * DD2 + o];
            float qq = tanhf(t);
            e[q] = wave_reduce_sum(qq * am[o]);
        }
        const float mxe = fmaxf(e[0], e[1]);
        float b0 = __expf(e[0] - mxe), b1 = __expf(e[1] - mxe);
        const float inv = 1.f / (b0 + b1);
        b0 *= inv; b1 *= inv;
        const float fus = b0 * ta0 + b1 * ta1;

        float p0 = ta0 * fcw[(o      ) * 2 + 0] + ta1 * fcw[(64 + o) * 2 + 0] + fus * fcw[(128 + o) * 2 + 0];
        float p1 = ta0 * fcw[(o      ) * 2 + 1] + ta1 * fcw[(64 + o) * 2 + 1] + fus * fcw[(128 + o) * 2 + 1];
        const float lg0 = wave_reduce_sum(p0) + fcb[0];
        const float lg1 = wave_reduce_sum(p1) + fcb[1];

        if (o == 0) {
            const float m2  = fmaxf(lg0, lg1);
            const float lse = m2 + logf(__expf(lg0 - m2) + __expf(lg1 - m2));
            out[(size_t)n * 2 + 0] = lg0 - lse;
            out[(size_t)n * 2 + 1] = lg1 - lse;
        }
    }
}

extern "C" void kernel_launch(void* const* d_in, const int* in_sizes, int n_in,
                              void* d_out, int out_size, void* d_ws, size_t ws_size,
                              hipStream_t stream)
{
    const int*   hadj = (const int*)d_in[0];
    const float* h    = (const float*)d_in[1];
    const float* w    = (const float*)d_in[2];
    const float* asrc = (const float*)d_in[3];
    const float* adst = (const float*)d_in[4];
    const float* bias = (const float*)d_in[5];
    const float* aw1  = (const float*)d_in[6];
    const float* aw2  = (const float*)d_in[7];
    const float* am   = (const float*)d_in[8];
    const float* fcw  = (const float*)d_in[9];
    const float* fcb  = (const float*)d_in[10];
    float* out = (float*)d_out;

    char* ws = (char*)d_ws;
    ushort4* hpq = (ushort4*)ws;                       // RR*NN*64*8 B = 6.29 MB
    ws += (size_t)RR * NN * FOUT * sizeof(ushort4);
    float4* sq = (float4*)ws;                          // RR*NN*16 B
    ws += (size_t)RR * NN * sizeof(float4);
    float4* dq = (float4*)ws;                          // RR*NN*16 B

    k1_proj<<<RR * NN / 4, 256, 0, stream>>>(h, w, asrc, adst, hpq, sq, dq);
    kSG<<<NWAVE / 4, 256, 0, stream>>>(
        hadj, hpq, sq, dq, bias, h, aw1, aw2, am, fcw, fcb, out);
}

// Round 17
// 77.964 us; speedup vs baseline: 1.3771x; 1.3771x over previous
//
#include <hip/hip_runtime.h>
#include <stdint.h>

#define NN 6144
#define NUSER 4096
#define RR 2
#define KK 3
#define FIN 25
#define FOUT 64
#define DD2 64
#define CAP 192

#define SCAN_BLOCKS (RR * NUSER / 4)   // 2048 blocks, 4 row-waves each
#define PROJ_BLOCKS (RR * NN / 4)      // 3072 blocks, 4 row-waves each

typedef int int4v __attribute__((ext_vector_type(4)));

__device__ __forceinline__ float wave_reduce_sum(float v) {
    #pragma unroll
    for (int off = 32; off >= 1; off >>= 1) v += __shfl_xor(v, off);
    return v;
}
__device__ __forceinline__ float wave_reduce_max(float v) {
    #pragma unroll
    for (int off = 32; off >= 1; off >>= 1) v = fmaxf(v, __shfl_xor(v, off));
    return v;
}
__device__ __forceinline__ unsigned short f2bf(float x) {   // RNE
    unsigned int u = __float_as_uint(x);
    unsigned int r = (u + 0x7fffu + ((u >> 16) & 1u)) >> 16;
    return (unsigned short)r;
}
__device__ __forceinline__ float bf2f(unsigned short b) {
    return __uint_as_float(((unsigned int)b) << 16);
}

// ---- kAP: heterogeneous grid. Scan blocks first (HBM long pole), proj
// blocks ride along.
__global__ __launch_bounds__(256) void kAP_scan_proj(
    const int* __restrict__ hadj, int* __restrict__ cnt, int* __restrict__ idx,
    const float* __restrict__ h, const float* __restrict__ w,
    const float* __restrict__ asrc, const float* __restrict__ adst,
    ushort4* __restrict__ hpq, float4* __restrict__ sq, float4* __restrict__ dq)
{
    const int wid  = threadIdx.x >> 6;
    const int lane = threadIdx.x & 63;

    if (blockIdx.x < SCAN_BLOCKS) {
        // ================= scan part: one wave per user row =================
        const int urow = blockIdx.x * 4 + wid;        // r*NUSER + n
        const int r    = urow / NUSER;
        const int n    = urow - r * NUSER;
        const int* rowp   = hadj + ((size_t)r * NN + n) * NN;
        int*       rowidx = idx  + (size_t)urow * CAP;
        const unsigned long long below = (1ull << lane) - 1ull;

        int base = 0;
        #pragma unroll 8
        for (int t = 0; t < 24; ++t) {
            const int m0 = t * 256 + lane * 4;
            const int4v v = *reinterpret_cast<const int4v*>(rowp + m0);
            const unsigned long long b0 = __ballot(v.x != 0);
            const unsigned long long b1 = __ballot(v.y != 0);
            const unsigned long long b2 = __ballot(v.z != 0);
            const unsigned long long b3 = __ballot(v.w != 0);
            const int n0 = __popcll(b0), n1 = __popcll(b1);
            const int n2 = __popcll(b2), n3 = __popcll(b3);
            const int o0 = base + __popcll(b0 & below);
            const int o1 = base + n0 + __popcll(b1 & below);
            const int o2 = base + n0 + n1 + __popcll(b2 & below);
            const int o3 = base + n0 + n1 + n2 + __popcll(b3 & below);
            if (v.x && o0 < CAP) rowidx[o0] = m0 + 0;
            if (v.y && o1 < CAP) rowidx[o1] = m0 + 1;
            if (v.z && o2 < CAP) rowidx[o2] = m0 + 2;
            if (v.w && o3 < CAP) rowidx[o3] = m0 + 3;
            base += n0 + n1 + n2 + n3;
        }
        if (lane == 0) cnt[urow] = base > CAP ? CAP : base;
    } else {
        // ================= proj part: one wave per (r,n), all n =============
        const int row = (blockIdx.x - SCAN_BLOCKS) * 4 + wid;   // r*NN + n
        const int r   = row / NN;
        const int n   = row % NN;

        const float* hrow = h + (size_t)n * FIN;
        float acc[KK];
        #pragma unroll
        for (int k = 0; k < KK; ++k) {
            const float* wp = w + ((size_t)(r * KK + k) * FIN) * FOUT + lane;
            float a = 0.f;
            #pragma unroll
            for (int f = 0; f < FIN; ++f) a += hrow[f] * wp[f * FOUT];
            acc[k] = a;
        }

        ushort4 pk;
        pk.x = f2bf(acc[0]); pk.y = f2bf(acc[1]); pk.z = f2bf(acc[2]); pk.w = 0;
        hpq[(size_t)row * FOUT + lane] = pk;

        float sv0 = wave_reduce_sum(acc[0] * asrc[(r * KK + 0) * FOUT + lane]);
        float sv1 = wave_reduce_sum(acc[1] * asrc[(r * KK + 1) * FOUT + lane]);
        float sv2 = wave_reduce_sum(acc[2] * asrc[(r * KK + 2) * FOUT + lane]);
        float dv0 = wave_reduce_sum(acc[0] * adst[(r * KK + 0) * FOUT + lane]);
        float dv1 = wave_reduce_sum(acc[1] * adst[(r * KK + 1) * FOUT + lane]);
        float dv2 = wave_reduce_sum(acc[2] * adst[(r * KK + 2) * FOUT + lane]);
        if (lane == 0) {
            sq[row] = make_float4(sv0, sv1, sv2, 0.f);
            dq[row] = make_float4(dv0, dv1, dv2, 0.f);
        }
    }
}

// ---- kBC: one 128-thread block per user node n. Wave r computes GAT row
// (r,n) -> LDS; barrier; wave 0 does semantic fusion + classifier.
__global__ __launch_bounds__(128) void kBC_gat_fuse(
    const int* __restrict__ cnt, const int* __restrict__ idx,
    const ushort4* __restrict__ hpq, const float4* __restrict__ sq,
    const float4* __restrict__ dq, const float* __restrict__ bias,
    const float* __restrict__ h, const float* __restrict__ aw1,
    const float* __restrict__ aw2, const float* __restrict__ am,
    const float* __restrict__ fcw, const float* __restrict__ fcb,
    float* __restrict__ out)
{
    const int n    = blockIdx.x;               // user node
    const int r    = threadIdx.x >> 6;         // wave id = relation
    const int lane = threadIdx.x & 63;
    const int urow = r * NUSER + n;

    __shared__ int   nbr_s[2][CAP];
    __shared__ float pw_s[2][3][CAP];
    __shared__ float emb_s[2][FOUT];
    int* nbr = nbr_s[r];
    float (*pw)[CAP] = pw_s[r];

    const int count = cnt[urow];
    const int* rowidx = idx + (size_t)urow * CAP;

    // ---- logits for all 3 heads (one float4 d-gather per neighbor)
    const float4 sv = sq[(size_t)r * NN + n];
    const float4* dqr = dq + (size_t)r * NN;
    float mx0 = -1e30f, mx1 = -1e30f, mx2 = -1e30f;
    for (int j = lane; j < count; j += 64) {
        const int nb = rowidx[j];
        nbr[j] = nb;
        const float4 dv = dqr[nb];
        float e0 = sv.x + dv.x; e0 = (e0 >= 0.f) ? e0 : 0.2f * e0;
        float e1 = sv.y + dv.y; e1 = (e1 >= 0.f) ? e1 : 0.2f * e1;
        float e2 = sv.z + dv.z; e2 = (e2 >= 0.f) ? e2 : 0.2f * e2;
        pw[0][j] = e0; pw[1][j] = e1; pw[2][j] = e2;
        mx0 = fmaxf(mx0, e0); mx1 = fmaxf(mx1, e1); mx2 = fmaxf(mx2, e2);
    }
    mx0 = wave_reduce_max(mx0);
    mx1 = wave_reduce_max(mx1);
    mx2 = wave_reduce_max(mx2);

    float ss0 = 0.f, ss1 = 0.f, ss2 = 0.f;
    for (int j = lane; j < count; j += 64) {
        float p0 = __expf(pw[0][j] - mx0); pw[0][j] = p0; ss0 += p0;
        float p1 = __expf(pw[1][j] - mx1); pw[1][j] = p1; ss1 += p1;
        float p2 = __expf(pw[2][j] - mx2); pw[2][j] = p2; ss2 += p2;
    }
    ss0 = wave_reduce_sum(ss0);
    ss1 = wave_reduce_sum(ss1);
    ss2 = wave_reduce_sum(ss2);

    // ---- PV gather: one ushort4 (3 heads bf16) coalesced load per neighbor
    const ushort4* hq = hpq + ((size_t)r * NN) * FOUT + lane;
    float a0 = 0.f, a1 = 0.f, a2 = 0.f;
    int j = 0;
    for (; j + 4 <= count; j += 4) {
        #pragma unroll
        for (int u = 0; u < 4; ++u) {
            const ushort4 v = hq[(size_t)nbr[j + u] * FOUT];
            a0 += pw[0][j + u] * bf2f(v.x);
            a1 += pw[1][j + u] * bf2f(v.y);
            a2 += pw[2][j + u] * bf2f(v.z);
        }
    }
    for (; j < count; ++j) {
        const ushort4 v = hq[(size_t)nbr[j] * FOUT];
        a0 += pw[0][j] * bf2f(v.x);
        a1 += pw[1][j] * bf2f(v.y);
        a2 += pw[2][j] * bf2f(v.z);
    }
    emb_s[r][lane] = (a0 / ss0 + a1 / ss1 + a2 / ss2) * (1.f / 3.f)
                   + bias[r * FOUT + lane];
    __syncthreads();

    // ---- semantic fusion + classifier + log_softmax (wave 0 only)
    if (r == 0) {
        const int o = lane;
        const float ta0 = emb_s[0][o];
        const float ta1 = emb_s[1][o];

        float fa = 0.f;
        const float* hrow = h + (size_t)n * FIN;
        #pragma unroll
        for (int f = 0; f < FIN; ++f) fa += hrow[f] * aw1[f * DD2 + o];

        float e[2];
        #pragma unroll
        for (int rr = 0; rr < 2; ++rr) {
            float t = fa;
            #pragma unroll 8
            for (int jj = 0; jj < FOUT; ++jj) t += emb_s[rr][jj] * aw2[jj * DD2 + o];
            float q = tanhf(t);
            e[rr] = wave_reduce_sum(q * am[o]);
        }
        const float mxe = fmaxf(e[0], e[1]);
        float b0 = __expf(e[0] - mxe), b1 = __expf(e[1] - mxe);
        const float inv = 1.f / (b0 + b1);
        b0 *= inv; b1 *= inv;
        const float fus = b0 * ta0 + b1 * ta1;

        float p0 = ta0 * fcw[(o      ) * 2 + 0] + ta1 * fcw[(64 + o) * 2 + 0] + fus * fcw[(128 + o) * 2 + 0];
        float p1 = ta0 * fcw[(o      ) * 2 + 1] + ta1 * fcw[(64 + o) * 2 + 1] + fus * fcw[(128 + o) * 2 + 1];
        const float lg0 = wave_reduce_sum(p0) + fcb[0];
        const float lg1 = wave_reduce_sum(p1) + fcb[1];

        if (o == 0) {
            const float m2  = fmaxf(lg0, lg1);
            const float lse = m2 + logf(__expf(lg0 - m2) + __expf(lg1 - m2));
            out[(size_t)n * 2 + 0] = lg0 - lse;
            out[(size_t)n * 2 + 1] = lg1 - lse;
        }
    }
}

extern "C" void kernel_launch(void* const* d_in, const int* in_sizes, int n_in,
                              void* d_out, int out_size, void* d_ws, size_t ws_size,
                              hipStream_t stream)
{
    const int*   hadj = (const int*)d_in[0];
    const float* h    = (const float*)d_in[1];
    const float* w    = (const float*)d_in[2];
    const float* asrc = (const float*)d_in[3];
    const float* adst = (const float*)d_in[4];
    const float* bias = (const float*)d_in[5];
    const float* aw1  = (const float*)d_in[6];
    const float* aw2  = (const float*)d_in[7];
    const float* am   = (const float*)d_in[8];
    const float* fcw  = (const float*)d_in[9];
    const float* fcb  = (const float*)d_in[10];
    float* out = (float*)d_out;

    char* ws = (char*)d_ws;
    ushort4* hpq = (ushort4*)ws;                       // RR*NN*64*8 B = 6.29 MB
    ws += (size_t)RR * NN * FOUT * sizeof(ushort4);
    float4* sq = (float4*)ws;                          // RR*NN*16 B
    ws += (size_t)RR * NN * sizeof(float4);
    float4* dq = (float4*)ws;                          // RR*NN*16 B
    ws += (size_t)RR * NN * sizeof(float4);
    int* cnt = (int*)ws;                               // RR*NUSER*4 B
    ws += (size_t)RR * NUSER * sizeof(int);
    int* idx = (int*)ws;                               // RR*NUSER*CAP*4 B = 6.3 MB

    kAP_scan_proj<<<SCAN_BLOCKS + PROJ_BLOCKS, 256, 0, stream>>>(
        hadj, cnt, idx, h, w, asrc, adst, hpq, sq, dq);
    kBC_gat_fuse<<<NUSER, 128, 0, stream>>>(
        cnt, idx, hpq, sq, dq, bias, h, aw1, aw2, am, fcw, fcb, out);
}